// Round 1
// baseline (1825.844 us; speedup 1.0000x reference)
//
#include <hip/hip_runtime.h>
#include <math.h>

// ---------------------------------------------------------------------------
// GCN predictor: 2x GCNConv(relu) -> mean pool + global feats -> MLP head
// N=100K nodes, E=3.2M directed edges, H=64.
// ---------------------------------------------------------------------------

__global__ void k_init_deg(int* __restrict__ deg, int n) {
    int i = blockIdx.x * blockDim.x + threadIdx.x;
    if (i < n) deg[i] = 1;  // self-loop
}

__global__ void k_deg(const int* __restrict__ dst, int E, int* __restrict__ deg) {
    int stride = gridDim.x * blockDim.x;
    for (int e = blockIdx.x * blockDim.x + threadIdx.x; e < E; e += stride)
        atomicAdd(&deg[dst[e]], 1);
}

__global__ void k_dinv(const int* __restrict__ deg, float* __restrict__ dinv, int n) {
    int i = blockIdx.x * blockDim.x + threadIdx.x;
    if (i < n) dinv[i] = rsqrtf((float)deg[i]);   // deg >= 1 always
}

// h1_pre[i,f] = sum_{k<5} x[i,k] * W1[k,f]   (wave per node, lane = feature)
__global__ void k_h1pre(const float* __restrict__ x, const float* __restrict__ W1,
                        float* __restrict__ out, int n) {
    int t = blockIdx.x * blockDim.x + threadIdx.x;
    int i = t >> 6, f = t & 63;
    if (i >= n) return;
    float acc = 0.f;
#pragma unroll
    for (int k = 0; k < 5; ++k) acc += x[i * 5 + k] * W1[k * 64 + f];
    out[i * 64 + f] = acc;
}

// One wave per edge: lane f does agg[dst*64+f] += norm * hpre[src*64+f].
// Edges [0,E) are real; [E, E+n) are self-loops.
__global__ void k_scatter(const int* __restrict__ src, const int* __restrict__ dst, int E,
                          const float* __restrict__ dinv,
                          const float* __restrict__ hpre, float* __restrict__ agg, int n) {
    int f = threadIdx.x & 63;
    int total = E + n;
    int wavesPerBlock = blockDim.x >> 6;
    int w0 = blockIdx.x * wavesPerBlock + (threadIdx.x >> 6);
    int wstride = gridDim.x * wavesPerBlock;
    for (int e = w0; e < total; e += wstride) {
        int s, d; float nrm;
        if (e < E) {
            s = src[e]; d = dst[e];
            nrm = dinv[s] * dinv[d];
        } else {
            s = d = e - E;
            float di = dinv[s];
            nrm = di * di;
        }
        atomicAdd(&agg[d * 64 + f], nrm * hpre[s * 64 + f]);
    }
}

// h2_pre[i,f] = sum_k relu(agg1[i,k] + b1[k]) * W2[k,f]   (wave per node)
__global__ void k_ffn(const float* __restrict__ agg1, const float* __restrict__ b1,
                      const float* __restrict__ W2, float* __restrict__ out, int n) {
    int t = blockIdx.x * blockDim.x + threadIdx.x;
    int i = t >> 6, f = t & 63;
    if (i >= n) return;
    float acc = 0.f;
#pragma unroll 8
    for (int k = 0; k < 64; ++k) {
        float h = fmaxf(agg1[i * 64 + k] + b1[k], 0.f);
        acc += h * W2[k * 64 + f];
    }
    out[i * 64 + f] = acc;
}

// red[f] += sum_i relu(agg2[i,f] + b2[f])    f in [0,64)
__global__ void k_reduce(const float* __restrict__ agg2, const float* __restrict__ b2,
                         float* __restrict__ red, int n) {
    __shared__ float lds[64];
    int f = threadIdx.x & 63;
    if (threadIdx.x < 64) lds[threadIdx.x] = 0.f;
    __syncthreads();
    int wavesPerBlock = blockDim.x >> 6;
    int w0 = blockIdx.x * wavesPerBlock + (threadIdx.x >> 6);
    int wstride = gridDim.x * wavesPerBlock;
    float acc = 0.f;
    for (int i = w0; i < n; i += wstride)
        acc += fmaxf(agg2[i * 64 + f] + b2[f], 0.f);
    atomicAdd(&lds[f], acc);
    __syncthreads();
    if (threadIdx.x < 64) atomicAdd(&red[threadIdx.x], lds[threadIdx.x]);
}

// global feature partial sums -> red[64..69]
__global__ void k_gf(const float* __restrict__ x, float* __restrict__ red, int n) {
    int stride = gridDim.x * blockDim.x;
    float s2 = 0, s3 = 0, s4 = 0, sm0 = 0, sm1 = 0, sc = 0;
    for (int i = blockIdx.x * blockDim.x + threadIdx.x; i < n; i += stride) {
        float x0 = x[i * 5 + 0], x1 = x[i * 5 + 1], x2 = x[i * 5 + 2];
        float x3 = x[i * 5 + 3], x4 = x[i * 5 + 4];
        s2 += x2; s3 += x3; s4 += x4;
        if (x2 == 1.0f) { sm0 += x0; sm1 += x1; sc += 1.f; }
    }
#pragma unroll
    for (int off = 32; off; off >>= 1) {
        s2 += __shfl_down(s2, off);
        s3 += __shfl_down(s3, off);
        s4 += __shfl_down(s4, off);
        sm0 += __shfl_down(sm0, off);
        sm1 += __shfl_down(sm1, off);
        sc += __shfl_down(sc, off);
    }
    if ((threadIdx.x & 63) == 0) {
        atomicAdd(&red[64], s2);
        atomicAdd(&red[65], s3);
        atomicAdd(&red[66], s4);
        atomicAdd(&red[67], sm0);
        atomicAdd(&red[68], sm1);
        atomicAdd(&red[69], sc);
    }
}

// Final head: emb = [mean(h2), gf(6)] (70), MLP 70->32->2, 2+3*sigmoid
__global__ void k_head(const float* __restrict__ red,
                       const float* __restrict__ l1w, const float* __restrict__ l1b,
                       const float* __restrict__ l2w, const float* __restrict__ l2b,
                       float* __restrict__ out, int n) {
    __shared__ float emb[70];
    __shared__ float hid[32];
    int t = threadIdx.x;
    if (t < 64) emb[t] = red[t] / (float)n;
    if (t == 0) {
        float n_comp = red[64], n_and = red[65], n_or = red[66];
        float cnt = red[69];
        float safe = fmaxf(cnt, 1.f);
        emb[64] = n_comp;
        emb[65] = n_and;
        emb[66] = n_or;
        emb[67] = n_and + n_or;
        emb[68] = cnt > 0.f ? red[67] / safe : 0.f;
        emb[69] = cnt > 0.f ? red[68] / safe : 0.f;
    }
    __syncthreads();
    if (t < 32) {
        float acc = l1b[t];
#pragma unroll
        for (int k = 0; k < 70; ++k) acc += emb[k] * l1w[k * 32 + t];
        hid[t] = fmaxf(acc, 0.f);
    }
    __syncthreads();
    if (t < 2) {
        float acc = l2b[t];
#pragma unroll
        for (int j = 0; j < 32; ++j) acc += hid[j] * l2w[j * 2 + t];
        out[t] = 2.0f + 3.0f / (1.0f + expf(-acc));
    }
}

extern "C" void kernel_launch(void* const* d_in, const int* in_sizes, int n_in,
                              void* d_out, int out_size, void* d_ws, size_t ws_size,
                              hipStream_t stream) {
    const float* x   = (const float*)d_in[0];
    const int*   ei  = (const int*)d_in[1];
    const float* w1  = (const float*)d_in[2];
    const float* b1  = (const float*)d_in[3];
    const float* w2  = (const float*)d_in[4];
    const float* b2  = (const float*)d_in[5];
    const float* l1w = (const float*)d_in[6];
    const float* l1b = (const float*)d_in[7];
    const float* l2w = (const float*)d_in[8];
    const float* l2b = (const float*)d_in[9];

    const int n = in_sizes[0] / 5;
    const int E = in_sizes[1] / 2;
    const int* src = ei;
    const int* dst = ei + E;

    size_t nf = (size_t)n * 64;
    float* bufA = (float*)d_ws;       // h1_pre, then h2_pre
    float* bufB = bufA + nf;          // agg1, then agg2
    int*   deg  = (int*)(bufB + nf);
    float* dinv = (float*)(deg + n);
    float* red  = dinv + n;           // 80 floats of partial sums

    hipMemsetAsync(bufB, 0, nf * sizeof(float), stream);   // agg1 = 0
    hipMemsetAsync(red, 0, 80 * sizeof(float), stream);

    const int B = 256;
    k_init_deg<<<(n + B - 1) / B, B, 0, stream>>>(deg, n);
    k_deg<<<2048, B, 0, stream>>>(dst, E, deg);
    k_dinv<<<(n + B - 1) / B, B, 0, stream>>>(deg, dinv, n);
    k_h1pre<<<(int)((nf + B - 1) / B), B, 0, stream>>>(x, w1, bufA, n);

    k_scatter<<<8192, B, 0, stream>>>(src, dst, E, dinv, bufA, bufB, n);   // agg1
    k_ffn<<<(int)((nf + B - 1) / B), B, 0, stream>>>(bufB, b1, w2, bufA, n); // h2_pre
    hipMemsetAsync(bufB, 0, nf * sizeof(float), stream);   // agg2 = 0
    k_scatter<<<8192, B, 0, stream>>>(src, dst, E, dinv, bufA, bufB, n);   // agg2

    k_reduce<<<1024, B, 0, stream>>>(bufB, b2, red, n);
    k_gf<<<256, B, 0, stream>>>(x, red, n);
    k_head<<<1, 64, 0, stream>>>(red, l1w, l1b, l2w, l2b, (float*)d_out, n);
}

// Round 2
// 892.241 us; speedup vs baseline: 2.0464x; 2.0464x over previous
//
#include <hip/hip_runtime.h>
#include <math.h>

// ---------------------------------------------------------------------------
// GCN predictor: 2x GCNConv(relu) -> mean pool + global feats -> MLP head
// N=100K nodes, E=3.2M directed edges, H=64.
// R2: replace fp32 atomic scatter (825MB HBM write-through per layer) with
// CSR counting-sort + register-accumulated gather (no fp atomics).
// ---------------------------------------------------------------------------

__global__ void k_init_deg(int* __restrict__ deg, int n) {
    int i = blockIdx.x * blockDim.x + threadIdx.x;
    if (i < n) deg[i] = 1;  // self-loop
}

__global__ void k_deg(const int* __restrict__ dst, int E, int* __restrict__ deg) {
    int stride = gridDim.x * blockDim.x;
    for (int e = blockIdx.x * blockDim.x + threadIdx.x; e < E; e += stride)
        atomicAdd(&deg[dst[e]], 1);
}

__global__ void k_dinv(const int* __restrict__ deg, float* __restrict__ dinv, int n) {
    int i = blockIdx.x * blockDim.x + threadIdx.x;
    if (i < n) dinv[i] = rsqrtf((float)deg[i]);   // deg >= 1 always
}

// --- two-level exclusive scan of cnt[i] = deg[i]-1 (real in-edges) ---------
__global__ void k_blocksum(const int* __restrict__ deg, int* __restrict__ bsum, int n) {
    __shared__ int lds[256];
    int i = blockIdx.x * 256 + threadIdx.x;
    lds[threadIdx.x] = (i < n) ? (deg[i] - 1) : 0;
    __syncthreads();
    for (int off = 128; off; off >>= 1) {
        if (threadIdx.x < off) lds[threadIdx.x] += lds[threadIdx.x + off];
        __syncthreads();
    }
    if (threadIdx.x == 0) bsum[blockIdx.x] = lds[0];
}

__global__ void k_scanbsum(int* __restrict__ bsum, int nb) {
    __shared__ int lds[512];
    int t = threadIdx.x;
    int v = (t < nb) ? bsum[t] : 0;
    lds[t] = v;
    __syncthreads();
    for (int off = 1; off < 512; off <<= 1) {
        int add = (t >= off) ? lds[t - off] : 0;
        __syncthreads();
        lds[t] += add;
        __syncthreads();
    }
    if (t < nb) bsum[t] = lds[t] - v;   // exclusive
}

__global__ void k_scan2(const int* __restrict__ deg, const int* __restrict__ bsum,
                        int* __restrict__ pos, int* __restrict__ cursor, int n) {
    __shared__ int lds[256];
    int i = blockIdx.x * 256 + threadIdx.x;
    int v = (i < n) ? (deg[i] - 1) : 0;
    lds[threadIdx.x] = v;
    __syncthreads();
    for (int off = 1; off < 256; off <<= 1) {
        int add = (threadIdx.x >= off) ? lds[threadIdx.x - off] : 0;
        __syncthreads();
        lds[threadIdx.x] += add;
        __syncthreads();
    }
    if (i < n) {
        int p = bsum[blockIdx.x] + lds[threadIdx.x] - v;  // exclusive
        pos[i] = p;
        cursor[i] = p;
    }
}

// counting sort: group src by dst. After this, cursor[d] == row_end(d).
__global__ void k_sort(const int* __restrict__ src, const int* __restrict__ dst, int E,
                       int* __restrict__ cursor, int* __restrict__ ssrc) {
    int stride = gridDim.x * blockDim.x;
    for (int e = blockIdx.x * blockDim.x + threadIdx.x; e < E; e += stride) {
        int d = dst[e];
        int slot = atomicAdd(&cursor[d], 1);
        ssrc[slot] = src[e];
    }
}

// h1_pre[i,f] = sum_{k<5} x[i,k] * W1[k,f]   (wave per node, lane = feature)
__global__ void k_h1pre(const float* __restrict__ x, const float* __restrict__ W1,
                        float* __restrict__ out, int n) {
    int t = blockIdx.x * blockDim.x + threadIdx.x;
    int i = t >> 6, f = t & 63;
    if (i >= n) return;
    float acc = 0.f;
#pragma unroll
    for (int k = 0; k < 5; ++k) acc += x[i * 5 + k] * W1[k * 64 + f];
    out[i * 64 + f] = acc;
}

// agg[d,f] = dinv[d] * ( dinv[d]*hpre[d,f] + sum_{s in N(d)} dinv[s]*hpre[s,f] )
// One wave per node; register accumulation; single coalesced write.
__global__ void k_gather(const int* __restrict__ pos, const int* __restrict__ rowend,
                         const int* __restrict__ ssrc, const float* __restrict__ dinv,
                         const float* __restrict__ hpre, float* __restrict__ agg, int n) {
    int t = blockIdx.x * blockDim.x + threadIdx.x;
    int i = t >> 6, f = t & 63;
    if (i >= n) return;
    int beg = pos[i], end = rowend[i];
    float dd = dinv[i];
    float acc = dd * hpre[(size_t)i * 64 + f];     // self loop (x dd below -> dd^2)
    int j = beg;
    for (; j + 3 < end; j += 4) {
        int s0 = ssrc[j], s1 = ssrc[j + 1], s2 = ssrc[j + 2], s3 = ssrc[j + 3];
        float a0 = dinv[s0] * hpre[(size_t)s0 * 64 + f];
        float a1 = dinv[s1] * hpre[(size_t)s1 * 64 + f];
        float a2 = dinv[s2] * hpre[(size_t)s2 * 64 + f];
        float a3 = dinv[s3] * hpre[(size_t)s3 * 64 + f];
        acc += (a0 + a1) + (a2 + a3);
    }
    for (; j < end; ++j) {
        int s = ssrc[j];
        acc += dinv[s] * hpre[(size_t)s * 64 + f];
    }
    agg[(size_t)i * 64 + f] = acc * dd;
}

// h2_pre[i,f] = sum_k relu(agg1[i,k] + b1[k]) * W2[k,f]   (wave per node)
__global__ void k_ffn(const float* __restrict__ agg1, const float* __restrict__ b1,
                      const float* __restrict__ W2, float* __restrict__ out, int n) {
    int t = blockIdx.x * blockDim.x + threadIdx.x;
    int i = t >> 6, f = t & 63;
    if (i >= n) return;
    float acc = 0.f;
#pragma unroll 8
    for (int k = 0; k < 64; ++k) {
        float h = fmaxf(agg1[i * 64 + k] + b1[k], 0.f);
        acc += h * W2[k * 64 + f];
    }
    out[i * 64 + f] = acc;
}

// red[f] += sum_i relu(agg2[i,f] + b2[f])    f in [0,64)
__global__ void k_reduce(const float* __restrict__ agg2, const float* __restrict__ b2,
                         float* __restrict__ red, int n) {
    __shared__ float lds[64];
    int f = threadIdx.x & 63;
    if (threadIdx.x < 64) lds[threadIdx.x] = 0.f;
    __syncthreads();
    int wavesPerBlock = blockDim.x >> 6;
    int w0 = blockIdx.x * wavesPerBlock + (threadIdx.x >> 6);
    int wstride = gridDim.x * wavesPerBlock;
    float acc = 0.f;
    for (int i = w0; i < n; i += wstride)
        acc += fmaxf(agg2[i * 64 + f] + b2[f], 0.f);
    atomicAdd(&lds[f], acc);
    __syncthreads();
    if (threadIdx.x < 64) atomicAdd(&red[threadIdx.x], lds[threadIdx.x]);
}

// global feature partial sums -> red[64..69]
__global__ void k_gf(const float* __restrict__ x, float* __restrict__ red, int n) {
    int stride = gridDim.x * blockDim.x;
    float s2 = 0, s3 = 0, s4 = 0, sm0 = 0, sm1 = 0, sc = 0;
    for (int i = blockIdx.x * blockDim.x + threadIdx.x; i < n; i += stride) {
        float x0 = x[i * 5 + 0], x1 = x[i * 5 + 1], x2 = x[i * 5 + 2];
        float x3 = x[i * 5 + 3], x4 = x[i * 5 + 4];
        s2 += x2; s3 += x3; s4 += x4;
        if (x2 == 1.0f) { sm0 += x0; sm1 += x1; sc += 1.f; }
    }
#pragma unroll
    for (int off = 32; off; off >>= 1) {
        s2 += __shfl_down(s2, off);
        s3 += __shfl_down(s3, off);
        s4 += __shfl_down(s4, off);
        sm0 += __shfl_down(sm0, off);
        sm1 += __shfl_down(sm1, off);
        sc += __shfl_down(sc, off);
    }
    if ((threadIdx.x & 63) == 0) {
        atomicAdd(&red[64], s2);
        atomicAdd(&red[65], s3);
        atomicAdd(&red[66], s4);
        atomicAdd(&red[67], sm0);
        atomicAdd(&red[68], sm1);
        atomicAdd(&red[69], sc);
    }
}

// Final head: emb = [mean(h2), gf(6)] (70), MLP 70->32->2, 2+3*sigmoid
__global__ void k_head(const float* __restrict__ red,
                       const float* __restrict__ l1w, const float* __restrict__ l1b,
                       const float* __restrict__ l2w, const float* __restrict__ l2b,
                       float* __restrict__ out, int n) {
    __shared__ float emb[70];
    __shared__ float hid[32];
    int t = threadIdx.x;
    if (t < 64) emb[t] = red[t] / (float)n;
    if (t == 0) {
        float n_comp = red[64], n_and = red[65], n_or = red[66];
        float cnt = red[69];
        float safe = fmaxf(cnt, 1.f);
        emb[64] = n_comp;
        emb[65] = n_and;
        emb[66] = n_or;
        emb[67] = n_and + n_or;
        emb[68] = cnt > 0.f ? red[67] / safe : 0.f;
        emb[69] = cnt > 0.f ? red[68] / safe : 0.f;
    }
    __syncthreads();
    if (t < 32) {
        float acc = l1b[t];
#pragma unroll
        for (int k = 0; k < 70; ++k) acc += emb[k] * l1w[k * 32 + t];
        hid[t] = fmaxf(acc, 0.f);
    }
    __syncthreads();
    if (t < 2) {
        float acc = l2b[t];
#pragma unroll
        for (int j = 0; j < 32; ++j) acc += hid[j] * l2w[j * 2 + t];
        out[t] = 2.0f + 3.0f / (1.0f + expf(-acc));
    }
}

extern "C" void kernel_launch(void* const* d_in, const int* in_sizes, int n_in,
                              void* d_out, int out_size, void* d_ws, size_t ws_size,
                              hipStream_t stream) {
    const float* x   = (const float*)d_in[0];
    const int*   ei  = (const int*)d_in[1];
    const float* w1  = (const float*)d_in[2];
    const float* b1  = (const float*)d_in[3];
    const float* w2  = (const float*)d_in[4];
    const float* b2  = (const float*)d_in[5];
    const float* l1w = (const float*)d_in[6];
    const float* l1b = (const float*)d_in[7];
    const float* l2w = (const float*)d_in[8];
    const float* l2b = (const float*)d_in[9];

    const int n = in_sizes[0] / 5;
    const int E = in_sizes[1] / 2;
    const int* src = ei;
    const int* dst = ei + E;

    size_t nf = (size_t)n * 64;
    float* bufA   = (float*)d_ws;          // h1_pre, then h2_pre
    float* bufB   = bufA + nf;             // agg1, then agg2
    int*   deg    = (int*)(bufB + nf);
    float* dinv   = (float*)(deg + n);
    int*   pos    = (int*)(dinv + n);      // row_start
    int*   cursor = pos + n;               // becomes row_end after sort
    int*   bsum   = cursor + n;            // 512 ints
    float* red    = (float*)(bsum + 512);  // 96 floats of partial sums
    int*   ssrc   = (int*)(red + 96);      // E ints, dst-sorted src

    const int B = 256;
    const int nb = (n + 255) / 256;        // 391 <= 512

    hipMemsetAsync(red, 0, 96 * sizeof(float), stream);

    k_init_deg<<<(n + B - 1) / B, B, 0, stream>>>(deg, n);
    k_deg<<<2048, B, 0, stream>>>(dst, E, deg);
    k_dinv<<<(n + B - 1) / B, B, 0, stream>>>(deg, dinv, n);

    k_blocksum<<<nb, 256, 0, stream>>>(deg, bsum, n);
    k_scanbsum<<<1, 512, 0, stream>>>(bsum, nb);
    k_scan2<<<nb, 256, 0, stream>>>(deg, bsum, pos, cursor, n);
    k_sort<<<2048, B, 0, stream>>>(src, dst, E, cursor, ssrc);

    k_h1pre<<<(int)((nf + B - 1) / B), B, 0, stream>>>(x, w1, bufA, n);

    k_gather<<<(int)((nf + B - 1) / B), B, 0, stream>>>(pos, cursor, ssrc, dinv, bufA, bufB, n);
    k_ffn<<<(int)((nf + B - 1) / B), B, 0, stream>>>(bufB, b1, w2, bufA, n);
    k_gather<<<(int)((nf + B - 1) / B), B, 0, stream>>>(pos, cursor, ssrc, dinv, bufA, bufB, n);

    k_reduce<<<1024, B, 0, stream>>>(bufB, b2, red, n);
    k_gf<<<256, B, 0, stream>>>(x, red, n);
    k_head<<<1, 64, 0, stream>>>(red, l1w, l1b, l2w, l2b, (float*)d_out, n);
}